// Round 2
// baseline (142.447 us; speedup 1.0000x reference)
//
#include <hip/hip_runtime.h>
#include <hip/hip_bf16.h>

// Problem constants (match reference)
#define BATCH 4096
#define NC    1024   // n_concepts (K)
#define NL    512    // n_lemmas   (N)
#define TSTEPS 50
#define GAMMA_C 0.95f
#define KAPPA_C 0.1f
#define FLOOR_C 1e-6f

#define MT  16            // rows per block (full-row fusion)
#define GK  32            // K per stage
#define NST (NC / GK)     // 32 stages

typedef __attribute__((ext_vector_type(8))) short short8;  // 8 bf16 = 4 VGPRs
typedef __attribute__((ext_vector_type(4))) float f32x4;   // MFMA C/D frag

// ---------------- split fp32 -> bf16 hi + bf16 lo (RNE both) ----------------
__device__ inline void split_bf16(float x, unsigned short& h, unsigned short& l) {
    unsigned u = __float_as_uint(x);
    unsigned rh = u + 0x7FFFu + ((u >> 16) & 1u);
    h = (unsigned short)(rh >> 16);
    float hf = __uint_as_float((unsigned)h << 16);
    float r = x - hf;
    unsigned v = __float_as_uint(r);
    unsigned rl = v + 0x7FFFu + ((v >> 16) & 1u);
    l = (unsigned short)(rl >> 16);
}

// packed split via v_cvt_pk_bf16_f32 (RNE)
__device__ __forceinline__ void split2_pk(float x0, float x1,
                                          unsigned& hp, unsigned& lp) {
    union { __hip_bfloat162 b; unsigned u; } ch, cl;
    ch.b = __float22bfloat162_rn(make_float2(x0, x1));
    hp = ch.u;
    const float hf0 = __uint_as_float(hp << 16);
    const float hf1 = __uint_as_float(hp & 0xFFFF0000u);
    cl.b = __float22bfloat162_rn(make_float2(x0 - hf0, x1 - hf1));
    lp = cl.u;
}

// W-only conversion: 512x1024 floats -> hi/lo bf16 (2.1 MB pass, ~1 us)
__global__ __launch_bounds__(256)
void convert_w(const float* __restrict__ W,
               unsigned short* __restrict__ Whi, unsigned short* __restrict__ Wlo) {
    const int fidx = (blockIdx.x * 256 + threadIdx.x) * 4;
    const float4 v = *(const float4*)(W + fidx);
    ushort4 h4, l4;
    split_bf16(v.x, h4.x, l4.x);
    split_bf16(v.y, h4.y, l4.y);
    split_bf16(v.z, h4.z, l4.z);
    split_bf16(v.w, h4.w, l4.w);
    *(ushort4*)(Whi + fidx) = h4;
    *(ushort4*)(Wlo + fidx) = l4;
}

// ------- full-wave (64-lane) sum, broadcast to all lanes, via DPP ----------
__device__ __forceinline__ float wave_sum_bcast(float x) {
    float f = x;
    f += __int_as_float(__builtin_amdgcn_update_dpp(
            0, __float_as_int(f), 0x111, 0xf, 0xf, true));   // row_shr:1
    f += __int_as_float(__builtin_amdgcn_update_dpp(
            0, __float_as_int(f), 0x112, 0xf, 0xf, true));   // row_shr:2
    f += __int_as_float(__builtin_amdgcn_update_dpp(
            0, __float_as_int(f), 0x114, 0xf, 0xf, true));   // row_shr:4
    f += __int_as_float(__builtin_amdgcn_update_dpp(
            0, __float_as_int(f), 0x118, 0xf, 0xf, true));   // row_shr:8
    f += __int_as_float(__builtin_amdgcn_update_dpp(
            0, __float_as_int(f), 0x142, 0xa, 0xf, true));   // row_bcast:15
    f += __int_as_float(__builtin_amdgcn_update_dpp(
            0, __float_as_int(f), 0x143, 0xc, 0xf, true));   // row_bcast:31
    return __int_as_float(__builtin_amdgcn_readlane(__float_as_int(f), 63));
}

// global -> LDS DMA, 16 B per lane; HW dest = readfirstlane(lds) + lane*16
__device__ __forceinline__ void glds16(const unsigned short* g, unsigned short* l) {
    __builtin_amdgcn_global_load_lds(
        (__attribute__((address_space(1))) void*)(g),
        (__attribute__((address_space(3))) void*)(l), 16, 0, 0);
}

// =================== fused full-row GEMM + recurrence =======================
// Block: M=16 rows x N=512 (ALL lemmas) x K=1024 (full) -> recurrence runs
// in-kernel, D-partials round trip (67 MB HBM) and 2 dispatches eliminated.
// Grid 256 blocks = 1/CU. LDS: double-buffered B hi/lo [512][32] (128 KB)
// + A hi/lo [16][32] (4 KB) = 132 KB (<=160 KB/CU, 1 block/CU).
// Per stage/CU: 64 KB B-DMA from L2 (~1170 cyc) vs 96 MFMA (~466 cyc):
// L2-BW-bound, ~16 us GEMM phase predicted.
__global__ __launch_bounds__(256)
void fused_gemm_iterate(const float* __restrict__ A,
                        const unsigned short* __restrict__ Whi,
                        const unsigned short* __restrict__ Wlo,
                        float* __restrict__ a_out,
                        float* __restrict__ sel_out, float* __restrict__ conf_out) {
    __shared__ unsigned short Bh[2][NL * GK];   // 32 KB each buf
    __shared__ unsigned short Bl[2][NL * GK];
    __shared__ unsigned short Ah[2][MT * GK];   // 1 KB each buf
    __shared__ unsigned short Al[2][MT * GK];

    const int tid  = threadIdx.x;
    const int lane = tid & 63;
    const int w    = tid >> 6;         // wave 0..3
    const int m0   = blockIdx.x * MT;

    // ---- B staging: wave w stages W rows [w*128, w*128+128), 8 calls x 16 rows
    const unsigned short* gBh = Whi + (size_t)(w * 128 + (lane >> 2)) * NC + (lane & 3) * 8;
    const unsigned short* gBl = Wlo + (size_t)(w * 128 + (lane >> 2)) * NC + (lane & 3) * 8;
    const int ldB = (w * 128) * GK + lane * 8;     // per-lane; HW uses lane0 base

    // ---- A staging (16 active lanes/wave): wave w stages A rows [w*4, w*4+4)
    const int ar = w * 4 + (lane >> 2);            // 0..15
    const int ak = (lane & 3) * 8;                 // 0,8,16,24
    const float* gA = A + (size_t)(m0 + ar) * NC + ak;
    const int ldA = ar * GK + ak;

    // ---- MFMA fragment addresses
    const int sr   = lane & 15;
    const int quad = lane >> 4;
    const int rA = sr * GK + quad * 8;                 // A row = sr (M=16)
    const int rB = (w * 128 + sr) * GK + quad * 8;     // + ni*16*GK

    f32x4 acc[8];
    #pragma unroll
    for (int i = 0; i < 8; ++i) acc[i] = (f32x4){0.f, 0.f, 0.f, 0.f};

    float4 a0v0, a0v1, a1v0, a1v1;   // distance-2 A-reg ping-pong

    #define STAGE_B(BUF, KO)                                              \
        do {                                                              \
            _Pragma("unroll")                                             \
            for (int c = 0; c < 8; ++c) {                                 \
                glds16(gBh + (size_t)c * 16 * NC + (KO),                  \
                       &Bh[BUF][ldB + c * 16 * GK]);                      \
                glds16(gBl + (size_t)c * 16 * NC + (KO),                  \
                       &Bl[BUF][ldB + c * 16 * GK]);                      \
            }                                                             \
        } while (0)

    #define LOADA(V0, V1, KO)                                             \
        do {                                                              \
            if (lane < 16) {                                              \
                V0 = *(const float4*)(gA + (KO));                         \
                V1 = *(const float4*)(gA + (KO) + 4);                     \
            }                                                             \
        } while (0)

    #define WRITEA(BUF, V0, V1)                                           \
        do {                                                              \
            if (lane < 16) {                                              \
                uint4 h, l;                                               \
                split2_pk(V0.x, V0.y, h.x, l.x);                          \
                split2_pk(V0.z, V0.w, h.y, l.y);                          \
                split2_pk(V1.x, V1.y, h.z, l.z);                          \
                split2_pk(V1.z, V1.w, h.w, l.w);                          \
                *(uint4*)&Ah[BUF][ldA] = h;                               \
                *(uint4*)&Al[BUF][ldA] = l;                               \
            }                                                             \
        } while (0)

    #define COMPUTE(CUR)                                                  \
        do {                                                              \
            short8 afh = *(const short8*)&Ah[CUR][rA];                    \
            short8 afl = *(const short8*)&Al[CUR][rA];                    \
            short8 bh[8], bl[8];                                          \
            _Pragma("unroll")                                             \
            for (int ni = 0; ni < 8; ++ni) {                              \
                bh[ni] = *(const short8*)&Bh[CUR][rB + ni * 16 * GK];     \
                bl[ni] = *(const short8*)&Bl[CUR][rB + ni * 16 * GK];     \
            }                                                             \
            _Pragma("unroll")                                             \
            for (int ni = 0; ni < 8; ++ni) {                              \
                acc[ni] = __builtin_amdgcn_mfma_f32_16x16x32_bf16(        \
                    afh, bh[ni], acc[ni], 0, 0, 0);                       \
                acc[ni] = __builtin_amdgcn_mfma_f32_16x16x32_bf16(        \
                    afh, bl[ni], acc[ni], 0, 0, 0);                       \
                acc[ni] = __builtin_amdgcn_mfma_f32_16x16x32_bf16(        \
                    afl, bh[ni], acc[ni], 0, 0, 0);                       \
            }                                                             \
        } while (0)

    // prologue
    LOADA(a0v0, a0v1, 0);
    LOADA(a1v0, a1v1, GK);
    WRITEA(0, a0v0, a0v1);
    STAGE_B(0, 0);
    __syncthreads();

    // stages 0..29 (pairs); stage s: stage buf for s+1, A-regs load for s+2
    for (int ss = 0; ss < NST - 2; ss += 2) {
        // even stage s=ss (cur=0)
        STAGE_B(1, (ss + 1) * GK);
        WRITEA(1, a1v0, a1v1);             // holds (ss+1)*GK
        LOADA(a0v0, a0v1, (ss + 2) * GK);
        COMPUTE(0);
        __syncthreads();

        // odd stage s=ss+1 (cur=1)
        STAGE_B(0, (ss + 2) * GK);
        WRITEA(0, a0v0, a0v1);             // holds (ss+2)*GK
        LOADA(a1v0, a1v1, (ss + 3) * GK);
        COMPUTE(1);
        __syncthreads();
    }
    // stage 30 (cur=0)
    STAGE_B(1, (NST - 1) * GK);
    WRITEA(1, a1v0, a1v1);                 // holds 31*GK
    COMPUTE(0);
    __syncthreads();
    // stage 31 (cur=1)
    COMPUTE(1);
    __syncthreads();

    // ---- redistribute D (16 x 512 fp32 = 32 KB) into LDS (reuse Bh[0]) ----
    float* Dl = (float*)&Bh[0][0];
    #pragma unroll
    for (int ni = 0; ni < 8; ++ni) {
        const int col = w * 128 + ni * 16 + sr;
        #pragma unroll
        for (int r = 0; r < 4; ++r)
            Dl[(quad * 4 + r) * NL + col] = acc[ni][r];
    }
    __syncthreads();

    // ---- recurrence: wave w owns rows [4w, 4w+4), lane covers 8 cols ------
    const int r0 = w * 4;
    float d[4][8];
    #pragma unroll
    for (int rr = 0; rr < 4; ++rr) {
        const float4 u0 = *(const float4*)&Dl[(r0 + rr) * NL + lane * 8];
        const float4 u1 = *(const float4*)&Dl[(r0 + rr) * NL + lane * 8 + 4];
        d[rr][0] = u0.x; d[rr][1] = u0.y; d[rr][2] = u0.z; d[rr][3] = u0.w;
        d[rr][4] = u1.x; d[rr][5] = u1.y; d[rr][6] = u1.z; d[rr][7] = u1.w;
    }

    float a[4][8];
    #pragma unroll
    for (int rr = 0; rr < 4; ++rr)
        #pragma unroll
        for (int j = 0; j < 8; ++j) a[rr][j] = 0.f;

    const float K1 = 1.0f + KAPPA_C;

    for (int t = 0; t < TSTEPS; ++t) {
        #pragma unroll
        for (int rr = 0; rr < 4; ++rr)
            #pragma unroll
            for (int j = 0; j < 8; ++j)
                a[rr][j] = fmaf(GAMMA_C, a[rr][j], d[rr][j]);

        float S[4];
        #pragma unroll
        for (int rr = 0; rr < 4; ++rr) {
            float t4a = a[rr][0] + a[rr][4], t4b = a[rr][1] + a[rr][5];
            float t4c = a[rr][2] + a[rr][6], t4d = a[rr][3] + a[rr][7];
            S[rr] = wave_sum_bcast((t4a + t4c) + (t4b + t4d));
        }

        #pragma unroll
        for (int rr = 0; rr < 4; ++rr) {
            const float h = -KAPPA_C * S[rr];
            #pragma unroll
            for (int j = 0; j < 8; ++j) {
                const float v = fmaf(K1, a[rr][j], h);
                a[rr][j] = v > 0.f ? v : 0.f;
            }
        }
    }

    // ---- selection + outputs, per row -------------------------------------
    #pragma unroll
    for (int rr = 0; rr < 4; ++rr) {
        const int row = m0 + r0 + rr;

        float m4a = fmaxf(a[rr][0], a[rr][4]), m4b = fmaxf(a[rr][1], a[rr][5]);
        float m4c = fmaxf(a[rr][2], a[rr][6]), m4d = fmaxf(a[rr][3], a[rr][7]);
        float peak = fmaxf(fmaxf(m4a, m4b), fmaxf(m4c, m4d));
        float s4a = a[rr][0] + a[rr][4], s4b = a[rr][1] + a[rr][5];
        float s4c = a[rr][2] + a[rr][6], s4d = a[rr][3] + a[rr][7];
        float ssum = wave_sum_bcast((s4a + s4b) + (s4c + s4d));

        #pragma unroll
        for (int m = 1; m < 64; m <<= 1)
            peak = fmaxf(peak, __shfl_xor(peak, m, 64));

        const float mean = ssum * (1.0f / (float)NL);
        const float conf = peak / fmaxf(mean, FLOOR_C);

        int idx = 0x7fffffff;
        #pragma unroll
        for (int j = 0; j < 8; ++j)
            if (a[rr][j] == peak) idx = min(idx, lane * 8 + j);
        #pragma unroll
        for (int m = 1; m < 64; m <<= 1)
            idx = min(idx, __shfl_xor(idx, m, 64));

        float4 o0, o1;
        o0.x = a[rr][0]; o0.y = a[rr][1]; o0.z = a[rr][2]; o0.w = a[rr][3];
        o1.x = a[rr][4]; o1.y = a[rr][5]; o1.z = a[rr][6]; o1.w = a[rr][7];
        float4* arp = (float4*)(a_out + (size_t)row * NL + lane * 8);
        arp[0] = o0; arp[1] = o1;

        if (lane == 0) {
            if (sel_out)  sel_out[row]  = (float)idx;
            if (conf_out) conf_out[row] = conf;
        }
    }
}

extern "C" void kernel_launch(void* const* d_in, const int* in_sizes, int n_in,
                              void* d_out, int out_size, void* d_ws, size_t ws_size,
                              hipStream_t stream) {
    const float* c_lex = (const float*)d_in[0];
    const float* W     = (const float*)d_in[1];
    // d_in[2] = a0 (zeros at every reset; recurrence inits a=0 directly)

    // workspace: Whi/Wlo only (2.1 MB) — D-partials eliminated
    unsigned short* Whi = (unsigned short*)d_ws;
    unsigned short* Wlo = Whi + (size_t)NL * NC;

    float* a_out = (float*)d_out;
    float* sel   = nullptr;
    float* conf  = nullptr;
    const int base = BATCH * NL;
    if (out_size >= base + 2 * BATCH) {        // (a, selected, confidence)
        sel  = a_out + base;
        conf = a_out + base + BATCH;
    } else if (out_size >= base + BATCH) {     // (a, confidence)
        conf = a_out + base;
    }

    // 1) W fp32 -> bf16 hi/lo
    convert_w<<<dim3(512), 256, 0, stream>>>(W, Whi, Wlo);

    // 2) fused full-row GEMM + 50-step recurrence + selection
    fused_gemm_iterate<<<dim3(BATCH / MT), 256, 0, stream>>>(
        c_lex, Whi, Wlo, a_out, sel, conf);
}

// Round 3
// 109.848 us; speedup vs baseline: 1.2968x; 1.2968x over previous
//
#include <hip/hip_runtime.h>
#include <hip/hip_bf16.h>

// Problem constants (match reference)
#define BATCH 4096
#define NC    1024   // n_concepts (K)
#define NL    512    // n_lemmas   (N)
#define TSTEPS 50
#define GAMMA_C 0.95f
#define KAPPA_C 0.1f
#define FLOOR_C 1e-6f

typedef __attribute__((ext_vector_type(8))) short short8;  // 8 bf16 = 4 VGPRs
typedef __attribute__((ext_vector_type(4))) float f32x4;   // MFMA C/D frag

// ---------------- packed split fp32 -> bf16 hi + bf16 lo (RNE both) --------
__device__ __forceinline__ void split2_pk(float x0, float x1,
                                          unsigned& hp, unsigned& lp) {
    union { __hip_bfloat162 b; unsigned u; } ch, cl;
    ch.b = __float22bfloat162_rn(make_float2(x0, x1));
    hp = ch.u;
    const float hf0 = __uint_as_float(hp << 16);
    const float hf1 = __uint_as_float(hp & 0xFFFF0000u);
    cl.b = __float22bfloat162_rn(make_float2(x0 - hf0, x1 - hf1));
    lp = cl.u;
}

// ---- convert BOTH W and A (c_lex) fp32 -> bf16 hi/lo, 8 floats/thread -----
#define W_FLOATS (NL * NC)                   // 524288
#define W_BLOCKS (W_FLOATS / (256 * 8))      // 256
#define A_BLOCKS ((BATCH * NC) / (256 * 8))  // 2048

__global__ __launch_bounds__(256)
void convert_hilo(const float* __restrict__ W, const float* __restrict__ A,
                  unsigned short* __restrict__ Whi, unsigned short* __restrict__ Wlo,
                  unsigned short* __restrict__ Ahi, unsigned short* __restrict__ Alo) {
    const int b = blockIdx.x;
    const float* src;
    unsigned short *dh, *dl;
    if (b < W_BLOCKS) {
        const size_t fidx = ((size_t)b * 256 + threadIdx.x) * 8;
        src = W + fidx; dh = Whi + fidx; dl = Wlo + fidx;
    } else {
        const size_t fidx = ((size_t)(b - W_BLOCKS) * 256 + threadIdx.x) * 8;
        src = A + fidx; dh = Ahi + fidx; dl = Alo + fidx;
    }
    const float4 v0 = ((const float4*)src)[0];
    const float4 v1 = ((const float4*)src)[1];
    uint4 h, l;
    split2_pk(v0.x, v0.y, h.x, l.x);
    split2_pk(v0.z, v0.w, h.y, l.y);
    split2_pk(v1.x, v1.y, h.z, l.z);
    split2_pk(v1.z, v1.w, h.w, l.w);
    *(uint4*)dh = h;
    *(uint4*)dl = l;
}

// ------- full-wave (64-lane) sum, broadcast to all lanes, via DPP ----------
__device__ __forceinline__ float wave_sum_bcast(float x) {
    float f = x;
    f += __int_as_float(__builtin_amdgcn_update_dpp(
            0, __float_as_int(f), 0x111, 0xf, 0xf, true));   // row_shr:1
    f += __int_as_float(__builtin_amdgcn_update_dpp(
            0, __float_as_int(f), 0x112, 0xf, 0xf, true));   // row_shr:2
    f += __int_as_float(__builtin_amdgcn_update_dpp(
            0, __float_as_int(f), 0x114, 0xf, 0xf, true));   // row_shr:4
    f += __int_as_float(__builtin_amdgcn_update_dpp(
            0, __float_as_int(f), 0x118, 0xf, 0xf, true));   // row_shr:8
    f += __int_as_float(__builtin_amdgcn_update_dpp(
            0, __float_as_int(f), 0x142, 0xa, 0xf, true));   // row_bcast:15
    f += __int_as_float(__builtin_amdgcn_update_dpp(
            0, __float_as_int(f), 0x143, 0xc, 0xf, true));   // row_bcast:31
    return __int_as_float(__builtin_amdgcn_readlane(__float_as_int(f), 63));
}

// global -> LDS DMA, 16 B per lane; HW dest = readfirstlane(lds) + lane*16
__device__ __forceinline__ void glds16(const unsigned short* g, unsigned short* l) {
    __builtin_amdgcn_global_load_lds(
        (__attribute__((address_space(1))) void*)(g),
        (__attribute__((address_space(3))) void*)(l), 16, 0, 0);
}

// ------------- MFMA GEMM: D = Ahi*Whi^T + Ahi*Wlo^T + Alo*Whi^T -------------
// R2 post-mortem: every __syncthreads() emits vmcnt(0), draining the
// prefetched stage's DMA with ~1 wave/SIMD to hide it (~5000 cyc/stage in
// BOTH prior structures). Fix = T3/T4 counted vmcnt: keep 2 stages (16 DMA
// ops/wave) in flight; per K-step wait vmcnt(8) (oldest stage only), raw
// s_barrier, compute, raw s_barrier, issue stage s+2. vmcnt never drains to
// 0 until the final step. splitK=2 (NST=16) halves the D round trip.
#define TM 128
#define TN 128
#define GK 32
#define SPLITK 2
#define NST (NC / SPLITK / GK)   // 16

__global__ __launch_bounds__(256)
void gemm_bf16x2(const unsigned short* __restrict__ Ahi, const unsigned short* __restrict__ Alo,
                 const unsigned short* __restrict__ Whi, const unsigned short* __restrict__ Wlo,
                 float* __restrict__ Dp) {
    // 2 buffers x 4 arrays (AsH, AsL, BsH, BsL) x [128][32] bf16 = 64 KB
    __shared__ unsigned short S[2][4][TM * GK];

    const int tid  = threadIdx.x;
    const int lane = tid & 63;
    const int w    = tid >> 6;
    const int m0 = blockIdx.x * TM;
    const int n0 = blockIdx.y * TN;
    const int kb = blockIdx.z * (NC / SPLITK);

    // staging: wave w owns rows [w*32, w*32+32) of each array; 2 calls/array.
    const int srow = w * 32 + (lane >> 2);
    const int scol = (lane & 3) * 8;
    const unsigned short* gAh = Ahi + (size_t)(m0 + srow) * NC + kb + scol;
    const unsigned short* gAl = Alo + (size_t)(m0 + srow) * NC + kb + scol;
    const unsigned short* gBh = Whi + (size_t)(n0 + srow) * NC + kb + scol;
    const unsigned short* gBl = Wlo + (size_t)(n0 + srow) * NC + kb + scol;
    const int ld0 = (w * 32) * GK + lane * 8;   // linear dest; HW: lane0 base + lane*16B

    const int mw   = (w >> 1) * 64;
    const int nw   = (w & 1) * 64;
    const int sr   = lane & 15;
    const int quad = lane >> 4;
    const int rA = (mw + sr) * GK + quad * 8;
    const int rB = (nw + sr) * GK + quad * 8;

    f32x4 acc[4][4];
    #pragma unroll
    for (int i = 0; i < 4; ++i)
        #pragma unroll
        for (int j = 0; j < 4; ++j)
            acc[i][j] = (f32x4){0.f, 0.f, 0.f, 0.f};

    // 8 glds16 per wave per stage -> vmcnt +8 per STAGE
    #define STAGE(buf, kofs)                                          \
        {                                                             \
            const int ko = (kofs);                                    \
            glds16(gAh + ko,           &S[buf][0][ld0]);              \
            glds16(gAh + ko + 16 * NC, &S[buf][0][ld0 + 16 * GK]);    \
            glds16(gAl + ko,           &S[buf][1][ld0]);              \
            glds16(gAl + ko + 16 * NC, &S[buf][1][ld0 + 16 * GK]);    \
            glds16(gBh + ko,           &S[buf][2][ld0]);              \
            glds16(gBh + ko + 16 * NC, &S[buf][2][ld0 + 16 * GK]);    \
            glds16(gBl + ko,           &S[buf][3][ld0]);              \
            glds16(gBl + ko + 16 * NC, &S[buf][3][ld0 + 16 * GK]);    \
        }

    // one pipelined K-step; VM = vmcnt immediate (8 steady-state, 0 last)
    #define KSTEP(CUR, VM, DO_STAGE, NEXTK)                                    \
        {                                                                      \
            asm volatile("s_waitcnt vmcnt(" #VM ")" ::: "memory");             \
            __builtin_amdgcn_sched_barrier(0);                                 \
            __builtin_amdgcn_s_barrier();                                      \
            __builtin_amdgcn_sched_barrier(0);                                 \
            short8 afh[4], afl[4], bfh[4], bfl[4];                             \
            _Pragma("unroll")                                                  \
            for (int mi = 0; mi < 4; ++mi) {                                   \
                afh[mi] = *(const short8*)&S[CUR][0][rA + mi * 16 * GK];       \
                afl[mi] = *(const short8*)&S[CUR][1][rA + mi * 16 * GK];       \
            }                                                                  \
            _Pragma("unroll")                                                  \
            for (int ni = 0; ni < 4; ++ni) {                                   \
                bfh[ni] = *(const short8*)&S[CUR][2][rB + ni * 16 * GK];       \
                bfl[ni] = *(const short8*)&S[CUR][3][rB + ni * 16 * GK];       \
            }                                                                  \
            _Pragma("unroll")                                                  \
            for (int mi = 0; mi < 4; ++mi) {                                   \
                _Pragma("unroll")                                              \
                for (int ni = 0; ni < 4; ++ni) {                               \
                    acc[mi][ni] = __builtin_amdgcn_mfma_f32_16x16x32_bf16(     \
                        afh[mi], bfh[ni], acc[mi][ni], 0, 0, 0);               \
                    acc[mi][ni] = __builtin_amdgcn_mfma_f32_16x16x32_bf16(     \
                        afh[mi], bfl[ni], acc[mi][ni], 0, 0, 0);               \
                    acc[mi][ni] = __builtin_amdgcn_mfma_f32_16x16x32_bf16(     \
                        afl[mi], bfh[ni], acc[mi][ni], 0, 0, 0);               \
                }                                                              \
            }                                                                  \
            __builtin_amdgcn_sched_barrier(0);                                 \
            __builtin_amdgcn_s_barrier();                                      \
            __builtin_amdgcn_sched_barrier(0);                                 \
            if (DO_STAGE) STAGE(CUR, NEXTK);                                   \
        }

    // prologue: stages 0 and 1 in flight (16 DMA ops/wave outstanding)
    STAGE(0, 0);
    STAGE(1, GK);

    // steady state: s = 0 .. NST-3 (buffer overwritten only after the
    // barrier that ends its readers -> no race; loads get a full step to land)
    #pragma unroll 2
    for (int s = 0; s < NST - 2; ++s)
        KSTEP((s & 1), 8, true, (s + 2) * GK);
    // peeled tail: s = NST-2 (cur=0), s = NST-1 (cur=1, full drain)
    KSTEP(0, 8, false, 0);
    KSTEP(1, 0, false, 0);

    // epilogue: C/D layout col = lane&15, row = quad*4 + reg  [m89/m91]
    float* Dz = Dp + (size_t)blockIdx.z * BATCH * NL;
    #pragma unroll
    for (int mi = 0; mi < 4; ++mi) {
        #pragma unroll
        for (int ni = 0; ni < 4; ++ni) {
            const int col = n0 + nw + ni * 16 + sr;
            #pragma unroll
            for (int r = 0; r < 4; ++r) {
                const int row = m0 + mw + mi * 16 + quad * 4 + r;
                Dz[(size_t)row * NL + col] = acc[mi][ni][r];
            }
        }
    }
}

// ------ 50-step recurrence + selection: 64 lanes per row, 8 cols/lane -------
template<int SK>
__global__ __launch_bounds__(256)
void iterate_select(const float* __restrict__ Dp,
                    float* __restrict__ a_out,
                    float* __restrict__ sel_out, float* __restrict__ conf_out) {
    const int lane = threadIdx.x & 63;
    const int wave = threadIdx.x >> 6;
    const int row  = blockIdx.x * 4 + wave;

    float d[8];
    {
        float4 v[SK][2];
        #pragma unroll
        for (int s = 0; s < SK; ++s) {
            const float4* ps = (const float4*)(Dp + (size_t)s * BATCH * NL
                                               + (size_t)row * NL + lane * 8);
            v[s][0] = ps[0];
            v[s][1] = ps[1];
        }
        d[0] = v[0][0].x; d[1] = v[0][0].y; d[2] = v[0][0].z; d[3] = v[0][0].w;
        d[4] = v[0][1].x; d[5] = v[0][1].y; d[6] = v[0][1].z; d[7] = v[0][1].w;
        #pragma unroll
        for (int s = 1; s < SK; ++s) {
            d[0] += v[s][0].x; d[1] += v[s][0].y; d[2] += v[s][0].z; d[3] += v[s][0].w;
            d[4] += v[s][1].x; d[5] += v[s][1].y; d[6] += v[s][1].z; d[7] += v[s][1].w;
        }
    }

    float a[8];
    #pragma unroll
    for (int j = 0; j < 8; ++j) a[j] = 0.f;

    const float K1 = 1.0f + KAPPA_C;

    for (int t = 0; t < TSTEPS; ++t) {
        #pragma unroll
        for (int j = 0; j < 8; ++j) a[j] = fmaf(GAMMA_C, a[j], d[j]);

        float t4a = a[0] + a[4], t4b = a[1] + a[5], t4c = a[2] + a[6], t4d = a[3] + a[7];
        float t2a = t4a + t4c, t2b = t4b + t4d;
        const float S = wave_sum_bcast(t2a + t2b);

        const float h = -KAPPA_C * S;
        #pragma unroll
        for (int j = 0; j < 8; ++j) {
            const float v = fmaf(K1, a[j], h);
            a[j] = v > 0.f ? v : 0.f;
        }
    }

    // ---- epilogue (runs once): peak, sum, confidence, first-index argmax ----
    float m4a = fmaxf(a[0], a[4]), m4b = fmaxf(a[1], a[5]);
    float m4c = fmaxf(a[2], a[6]), m4d = fmaxf(a[3], a[7]);
    float peak = fmaxf(fmaxf(m4a, m4b), fmaxf(m4c, m4d));
    float s4a = a[0] + a[4], s4b = a[1] + a[5], s4c = a[2] + a[6], s4d = a[3] + a[7];
    float ssum = wave_sum_bcast((s4a + s4b) + (s4c + s4d));

    #pragma unroll
    for (int m = 1; m < 64; m <<= 1)
        peak = fmaxf(peak, __shfl_xor(peak, m, 64));

    const float mean = ssum * (1.0f / (float)NL);
    const float conf = peak / fmaxf(mean, FLOOR_C);

    int idx = 0x7fffffff;
    #pragma unroll
    for (int j = 0; j < 8; ++j)
        if (a[j] == peak) idx = min(idx, lane * 8 + j);
    #pragma unroll
    for (int m = 1; m < 64; m <<= 1)
        idx = min(idx, __shfl_xor(idx, m, 64));

    float4* ar = (float4*)(a_out + (size_t)row * NL + lane * 8);
    float4 o0, o1;
    o0.x = a[0]; o0.y = a[1]; o0.z = a[2]; o0.w = a[3];
    o1.x = a[4]; o1.y = a[5]; o1.z = a[6]; o1.w = a[7];
    ar[0] = o0; ar[1] = o1;

    if (lane == 0) {
        if (sel_out)  sel_out[row]  = (float)idx;
        if (conf_out) conf_out[row] = conf;
    }
}

extern "C" void kernel_launch(void* const* d_in, const int* in_sizes, int n_in,
                              void* d_out, int out_size, void* d_ws, size_t ws_size,
                              hipStream_t stream) {
    const float* c_lex = (const float*)d_in[0];
    const float* W     = (const float*)d_in[1];
    // d_in[2] = a0 (zeros at every reset; recurrence inits a=0 directly)

    // workspace: 2 D-partials (16.8 MB) + Whi/Wlo (2.1 MB) + Ahi/Alo (16.8 MB)
    float* D = (float*)d_ws;
    unsigned short* Whi = (unsigned short*)(D + (size_t)SPLITK * BATCH * NL);
    unsigned short* Wlo = Whi + (size_t)NL * NC;
    unsigned short* Ahi = Wlo + (size_t)NL * NC;
    unsigned short* Alo = Ahi + (size_t)BATCH * NC;

    float* a_out = (float*)d_out;
    float* sel   = nullptr;
    float* conf  = nullptr;
    const int base = BATCH * NL;
    if (out_size >= base + 2 * BATCH) {        // (a, selected, confidence)
        sel  = a_out + base;
        conf = a_out + base + BATCH;
    } else if (out_size >= base + BATCH) {     // (a, confidence)
        conf = a_out + base;
    }

    // 1) W and A fp32 -> bf16 hi/lo (one streaming pass, ~44 MB)
    convert_hilo<<<dim3(W_BLOCKS + A_BLOCKS), 256, 0, stream>>>(
        W, c_lex, Whi, Wlo, Ahi, Alo);

    // 2) MFMA GEMM, counted-vmcnt pipeline, splitK=2 -> grid (32,4,2)
    gemm_bf16x2<<<dim3(BATCH / TM, NL / TN, SPLITK), 256, 0, stream>>>(
        Ahi, Alo, Whi, Wlo, D);

    // 3) recurrence + selection: 1 row/wave, 4 waves/SIMD, DPP row-sum
    iterate_select<SPLITK><<<dim3(BATCH / 4), 256, 0, stream>>>(D, a_out, sel, conf);
}